// Round 1
// 5698.667 us; speedup vs baseline: 3.1539x; 3.1539x over previous
//
#include <hip/hip_runtime.h>
#include <hip/hip_bf16.h>
#include <math.h>

typedef __bf16 bf16_8 __attribute__((ext_vector_type(8)));
typedef float  f32x4  __attribute__((ext_vector_type(4)));

#define B_   32
#define T_   512
#define H_   1024
#define G_   4096   // 4*H
#define E_   300
#define EP_  320
#define CT_  128    // time chunk
#define NCH  4      // chunks

// ---------------- workspace layout (bytes) ----------------
constexpr size_t OFF_HBUF  = 0;                         // 2 layers x 2 slots x 2 dirs x 32x1024 bf16
constexpr size_t OFF_FLAGS = 524288;                    // 2 layers x 2 dirs x 128 x 32 u32 = 131072
constexpr size_t SZ_ZERO   = OFF_FLAGS + 131072;        // 655360
constexpr size_t OFF_CBUF  = SZ_ZERO;                   // 2 x 32 x 1024 f32 = 262144
constexpr size_t OFF_H2F   = OFF_CBUF + 262144;         // 917504
constexpr size_t OFF_H2B   = OFF_H2F + 65536;
constexpr size_t OFF_W0F   = OFF_H2B + 65536;           // 1048576, 4096x320 bf16
constexpr size_t OFF_W0B   = OFF_W0F + 2621440;
constexpr size_t OFF_W1F   = OFF_W0B + 2621440;         // 6291456, 4096x2048 bf16
constexpr size_t OFF_W1B   = OFF_W1F + 16777216;
constexpr size_t OFF_EMB   = OFF_W1B + 16777216;        // 39845888, 50000x320 bf16
constexpr size_t OFF_OUTF  = OFF_EMB + 32000000;        // 71845888, 32x512x1024 bf16
constexpr size_t OFF_OUTB  = OFF_OUTF + 33554432;
constexpr size_t OFF_XPF   = OFF_OUTB + 33554432;       // 138954752, chunk 32x128x4096 bf16
constexpr size_t OFF_XPB   = OFF_XPF + 33554432;
constexpr size_t WS_NEED   = OFF_XPB + 33554432;        // 206,063,616 (~196.5 MiB; ws known >= 326 MiB)

// LDS partition for recurrent kernel
#define WSTR 1032
constexpr int LDS_W  = 0;
constexpr int LDS_H  = 32 * WSTR * 2;                   // 66048
constexpr int LDS_G  = LDS_H + 32 * WSTR * 2;           // 132096
constexpr int LDS_C  = LDS_G + 32 * 36 * 4;             // 136704
constexpr int LDS_L  = LDS_C + 32 * 8 * 4;              // 137728
constexpr int SMEM_REC = LDS_L + 128;                   // 137856

__device__ __forceinline__ float sigf(float x) { return 1.f / (1.f + __expf(-x)); }

__device__ __forceinline__ bf16_8 cvt8(f32x4 lo, f32x4 hi) {
    bf16_8 v;
    #pragma unroll
    for (int e = 0; e < 4; ++e) { v[e] = (__bf16)lo[e]; v[4 + e] = (__bf16)hi[e]; }
    return v;
}

// ---------------- weight/embedding conversion kernels ----------------
__global__ void pad_w0(const float* __restrict__ wf, const float* __restrict__ wb,
                       __bf16* __restrict__ of, __bf16* __restrict__ ob) {
    int r = blockIdx.x, dir = blockIdx.y, k = threadIdx.x;   // block 320
    const float* s = dir ? wb : wf;
    __bf16* d = (dir ? ob : of) + (size_t)r * EP_;
    d[k] = (k < E_) ? (__bf16)s[(size_t)r * E_ + k] : (__bf16)0.f;
}

__global__ void cvt_w1(const float* __restrict__ wf, const float* __restrict__ wb,
                       __bf16* __restrict__ of, __bf16* __restrict__ ob) {
    int n = blockIdx.x;
    const float* s = (blockIdx.y ? wb : wf) + (size_t)n * 2048;
    __bf16* d = (blockIdx.y ? ob : of) + (size_t)n * 2048;
    for (int k = threadIdx.x; k < 2048; k += 256) d[k] = (__bf16)s[k];
}

__global__ void cvt_emb(const float* __restrict__ emb, __bf16* __restrict__ embp) {
    int v = blockIdx.x, k = threadIdx.x;                     // block 320
    embp[(size_t)v * EP_ + k] = (k < E_) ? (__bf16)emb[(size_t)v * E_ + k] : (__bf16)0.f;
}

// ---------------- layer-0 chunk GEMM (M=4096 rows = 32b x 128t), K=320 ----------------
__global__ __launch_bounds__(256) void gemm_l0c(
    const int* __restrict__ texts, const int* __restrict__ lens,
    const __bf16* __restrict__ embp, const __bf16* __restrict__ W,
    const float* __restrict__ bih, const float* __restrict__ bhh,
    __bf16* __restrict__ D, int dir, int t0) {
    constexpr int LDT = 40;
    __shared__ __bf16 As[128 * LDT];
    __shared__ __bf16 Bs[128 * LDT];
    int m0 = (blockIdx.x >> 5) * 128, n0 = (blockIdx.x & 31) * 128;
    int tid = threadIdx.x;
    int rr = tid >> 2, c8 = (tid & 3) * 8;
    const __bf16* pA[2]; const __bf16* pB[2];
    #pragma unroll
    for (int s = 0; s < 2; ++s) {
        int row = m0 + rr + s * 64;
        int b = row >> 7, t = t0 + (row & 127);
        int tt = t;
        if (dir) { int L = lens[b]; tt = L - 1 - t; if (tt < 0) tt = 0; }
        pA[s] = embp + (size_t)texts[b * T_ + tt] * EP_;
        pB[s] = W + (size_t)(n0 + rr + s * 64) * EP_;
    }
    int lane = tid & 63, wid = tid >> 6;
    int wm = (wid >> 1) * 64, wn = (wid & 1) * 64;
    int row16 = lane & 15, quad = lane >> 4;
    bf16_8 apf[2], bpf[2];
    #pragma unroll
    for (int s = 0; s < 2; ++s) {
        apf[s] = *(const bf16_8*)(pA[s] + c8);
        bpf[s] = *(const bf16_8*)(pB[s] + c8);
    }
    f32x4 acc[4][4] = {};
    for (int k0 = 0; k0 < EP_; k0 += 32) {
        #pragma unroll
        for (int s = 0; s < 2; ++s) {
            *(bf16_8*)&As[(rr + s * 64) * LDT + c8] = apf[s];
            *(bf16_8*)&Bs[(rr + s * 64) * LDT + c8] = bpf[s];
        }
        __syncthreads();
        if (k0 + 32 < EP_) {
            int k8 = k0 + 32 + c8;
            #pragma unroll
            for (int s = 0; s < 2; ++s) {
                apf[s] = *(const bf16_8*)(pA[s] + k8);
                bpf[s] = *(const bf16_8*)(pB[s] + k8);
            }
        }
        bf16_8 a[4], b[4];
        #pragma unroll
        for (int i = 0; i < 4; ++i) a[i] = *(const bf16_8*)&As[(wm + i * 16 + row16) * LDT + quad * 8];
        #pragma unroll
        for (int j = 0; j < 4; ++j) b[j] = *(const bf16_8*)&Bs[(wn + j * 16 + row16) * LDT + quad * 8];
        #pragma unroll
        for (int i = 0; i < 4; ++i)
            #pragma unroll
            for (int j = 0; j < 4; ++j)
                acc[i][j] = __builtin_amdgcn_mfma_f32_16x16x32_bf16(a[i], b[j], acc[i][j], 0, 0, 0);
        __syncthreads();
    }
    #pragma unroll
    for (int j = 0; j < 4; ++j) {
        int col = n0 + wn + j * 16 + row16;
        float bias = bih[col] + bhh[col];
        #pragma unroll
        for (int i = 0; i < 4; ++i) {
            int rowb = m0 + wm + i * 16 + quad * 4;
            #pragma unroll
            for (int r = 0; r < 4; ++r)
                D[(size_t)(rowb + r) * G_ + col] = (__bf16)(acc[i][j][r] + bias);
        }
    }
}

// ---------------- layer-1 chunk GEMM, concat+reverse gather, K=2048, W bf16 ----------------
__global__ __launch_bounds__(256) void gemm_l1c(
    const __bf16* __restrict__ outf, const __bf16* __restrict__ outbr,
    const int* __restrict__ lens, const __bf16* __restrict__ W,
    const float* __restrict__ bih, const float* __restrict__ bhh,
    __bf16* __restrict__ D, int dir, int t0) {
    constexpr int LDT = 40;
    __shared__ __bf16 As[128 * LDT];
    __shared__ __bf16 Bs[128 * LDT];
    int m0 = (blockIdx.x >> 5) * 128, n0 = (blockIdx.x & 31) * 128;
    int tid = threadIdx.x;
    int rr = tid >> 2, c8 = (tid & 3) * 8;
    const __bf16* pLo[2]; const __bf16* pHi[2]; const __bf16* pB[2];
    #pragma unroll
    for (int s = 0; s < 2; ++s) {
        int row = m0 + rr + s * 64;
        int b = row >> 7, t = t0 + (row & 127);
        int L = lens[b];
        int rev = L - 1 - t; if (rev < 0) rev = 0;
        int tf = dir ? rev : t;
        int tb = dir ? t : rev;
        pLo[s] = outf  + ((size_t)b * T_ + tf) * H_;
        pHi[s] = outbr + ((size_t)b * T_ + tb) * H_;
        pB[s]  = W + (size_t)(n0 + rr + s * 64) * (2 * H_);
    }
    int lane = tid & 63, wid = tid >> 6;
    int wm = (wid >> 1) * 64, wn = (wid & 1) * 64;
    int row16 = lane & 15, quad = lane >> 4;
    bf16_8 apf[2], bpf[2];
    #pragma unroll
    for (int s = 0; s < 2; ++s) {
        apf[s] = *(const bf16_8*)(pLo[s] + c8);
        bpf[s] = *(const bf16_8*)(pB[s] + c8);
    }
    f32x4 acc[4][4] = {};
    for (int k0 = 0; k0 < 2 * H_; k0 += 32) {
        #pragma unroll
        for (int s = 0; s < 2; ++s) {
            *(bf16_8*)&As[(rr + s * 64) * LDT + c8] = apf[s];
            *(bf16_8*)&Bs[(rr + s * 64) * LDT + c8] = bpf[s];
        }
        __syncthreads();
        if (k0 + 32 < 2 * H_) {
            int k8 = k0 + 32 + c8;
            #pragma unroll
            for (int s = 0; s < 2; ++s) {
                const __bf16* src = (k8 < H_) ? pLo[s] + k8 : pHi[s] + (k8 - H_);
                apf[s] = *(const bf16_8*)src;
                bpf[s] = *(const bf16_8*)&pB[s][k8];
            }
        }
        bf16_8 a[4], b[4];
        #pragma unroll
        for (int i = 0; i < 4; ++i) a[i] = *(const bf16_8*)&As[(wm + i * 16 + row16) * LDT + quad * 8];
        #pragma unroll
        for (int j = 0; j < 4; ++j) b[j] = *(const bf16_8*)&Bs[(wn + j * 16 + row16) * LDT + quad * 8];
        #pragma unroll
        for (int i = 0; i < 4; ++i)
            #pragma unroll
            for (int j = 0; j < 4; ++j)
                acc[i][j] = __builtin_amdgcn_mfma_f32_16x16x32_bf16(a[i], b[j], acc[i][j], 0, 0, 0);
        __syncthreads();
    }
    #pragma unroll
    for (int j = 0; j < 4; ++j) {
        int col = n0 + wn + j * 16 + row16;
        float bias = bih[col] + bhh[col];
        #pragma unroll
        for (int i = 0; i < 4; ++i) {
            int rowb = m0 + wm + i * 16 + quad * 4;
            #pragma unroll
            for (int r = 0; r < 4; ++r)
                D[(size_t)(rowb + r) * G_ + col] = (__bf16)(acc[i][j][r] + bias);
        }
    }
}

// ---------------- persistent recurrent kernel, chunked, flag barrier ----------------
// 256 blocks x 256 thr; dir = blk>>7; block owns 8 hidden units. xp = chunk [32][CT_][4096].
// Cross-block h exchange uses fine-grained coherent (sc0 sc1, L2-bypassing) stores/loads
// instead of threadfence/acquire, which on gfx950 lower to whole-L2 buffer_wbl2/buffer_inv
// per step per block -- that cache maintenance was the dominant per-step cost.
__global__ __launch_bounds__(256) void lstm_rec(
    const __bf16* __restrict__ xp_f, const __bf16* __restrict__ xp_b,
    const float* __restrict__ whh_f, const float* __restrict__ whh_b,
    const int* __restrict__ lens,
    __bf16* __restrict__ hbuf,           // layer base: [2 slots][2 dirs][32][1024]
    float* __restrict__ cbuf,            // [2 dirs][32][1024]
    __bf16* __restrict__ out_f, __bf16* __restrict__ out_b,
    unsigned* __restrict__ flags,        // layer base: [2 dirs][128][32]
    int t0, int seq) {
    extern __shared__ char smem[];
    __bf16* Wl = (__bf16*)(smem + LDS_W);
    __bf16* Hl = (__bf16*)(smem + LDS_H);
    float*  Gl = (float*)(smem + LDS_G);
    float*  Cl = (float*)(smem + LDS_C);
    int*    Ll = (int*)(smem + LDS_L);

    int blk = blockIdx.x;
    int dir = blk >> 7;
    int myb = blk & 127;
    int j0  = myb * 8;
    int tid = threadIdx.x;
    const __bf16* xp  = dir ? xp_b : xp_f;
    const float*  whh = dir ? whh_b : whh_f;
    __bf16* outp = dir ? out_b : out_f;
    unsigned* myflags = flags + dir * 128 * 32;

    int em = tid >> 3, eu = tid & 7;
    // stage W_hh slice (fp32->bf16): n = gate*8+unit -> whh row gate*1024 + j0 + unit
    for (int i = tid; i < 32 * 128; i += 256) {
        int n = i >> 7, k8 = (i & 127) * 8;
        int grow = (n >> 3) * H_ + j0 + (n & 7);
        f32x4 lo = *(const f32x4*)&whh[(size_t)grow * H_ + k8];
        f32x4 hi = *(const f32x4*)&whh[(size_t)grow * H_ + k8 + 4];
        *(bf16_8*)&Wl[n * WSTR + k8] = cvt8(lo, hi);
    }
    if (tid < 32) Ll[tid] = lens[tid];
    Cl[tid] = (t0 == 0) ? 0.f : cbuf[dir * (B_ * H_) + em * H_ + j0 + eu];
    __syncthreads();

    int lane = tid & 63, wid = tid >> 6;
    int row16 = lane & 15, quad = lane >> 4;
    int m0 = (wid >> 1) * 16, n0 = (wid & 1) * 16;
    int tend = t0 + CT_;

    for (int t = t0; t < tend; ++t) {
        // prefetch this step's xp (independent of h)
        size_t xbase = ((size_t)em * CT_ + (t - t0)) * G_ + j0 + eu;
        __bf16 xg0 = xp[xbase];
        __bf16 xg1 = xp[xbase + H_];
        __bf16 xg2 = xp[xbase + 2 * H_];
        __bf16 xg3 = xp[xbase + 3 * H_];
        // stage h(t) from slot (t&1): coherent (L2-bypassing) loads, fully pipelined
        const __bf16* hs = hbuf + (size_t)((t & 1) * 2 + dir) * (B_ * H_);
        f32x4 hreg[16];
        #pragma unroll
        for (int s = 0; s < 16; ++s) {
            int idx = tid + s * 256;
            int mm = idx >> 7, k8 = (idx & 127) * 8;
            const __bf16* p = hs + mm * H_ + k8;
            asm volatile("global_load_dwordx4 %0, %1, off sc0 sc1"
                         : "=v"(hreg[s]) : "v"(p));
        }
        asm volatile("s_waitcnt vmcnt(0)" ::: "memory");
        __builtin_amdgcn_sched_barrier(0);
        #pragma unroll
        for (int s = 0; s < 16; ++s) {
            int idx = tid + s * 256;
            int mm = idx >> 7, k8 = (idx & 127) * 8;
            *(bf16_8*)&Hl[mm * WSTR + k8] = *(bf16_8*)&hreg[s];
        }
        __syncthreads();
        // gates(32x32) = h(32x1024) @ Wslice(32x1024)^T
        f32x4 acc0 = {0.f, 0.f, 0.f, 0.f}, acc1 = {0.f, 0.f, 0.f, 0.f};
        #pragma unroll
        for (int kc = 0; kc < 32; kc += 2) {
            bf16_8 a0 = *(const bf16_8*)&Hl[(m0 + row16) * WSTR + kc * 32 + quad * 8];
            bf16_8 b0 = *(const bf16_8*)&Wl[(n0 + row16) * WSTR + kc * 32 + quad * 8];
            acc0 = __builtin_amdgcn_mfma_f32_16x16x32_bf16(a0, b0, acc0, 0, 0, 0);
            bf16_8 a1 = *(const bf16_8*)&Hl[(m0 + row16) * WSTR + (kc + 1) * 32 + quad * 8];
            bf16_8 b1 = *(const bf16_8*)&Wl[(n0 + row16) * WSTR + (kc + 1) * 32 + quad * 8];
            acc1 = __builtin_amdgcn_mfma_f32_16x16x32_bf16(a1, b1, acc1, 0, 0, 0);
        }
        #pragma unroll
        for (int r = 0; r < 4; ++r)
            Gl[(m0 + quad * 4 + r) * 36 + n0 + row16] = acc0[r] + acc1[r];
        __syncthreads();
        // elementwise LSTM cell for (batch em, unit j0+eu)
        {
            float pi = Gl[em * 36 + eu]      + (float)xg0;
            float pf = Gl[em * 36 + 8 + eu]  + (float)xg1;
            float pg = Gl[em * 36 + 16 + eu] + (float)xg2;
            float po = Gl[em * 36 + 24 + eu] + (float)xg3;
            float co = Cl[tid];
            float cn = sigf(pf) * co + sigf(pi) * tanhf(pg);
            float hn = sigf(po) * tanhf(cn);
            __bf16 heff;
            if (t < Ll[em]) { Cl[tid] = cn; heff = (__bf16)hn; }
            else            { heff = Hl[em * WSTR + j0 + eu]; }
            // coherent write-through h store (visible at LLC once vmcnt retires)
            {
                __bf16* hp = &hbuf[(size_t)(((t + 1) & 1) * 2 + dir) * (B_ * H_) + em * H_ + j0 + eu];
                unsigned hv = (unsigned)*(unsigned short*)&heff;
                asm volatile("global_store_short %0, %1, off sc0 sc1"
                             :: "v"(hp), "v"(hv) : "memory");
            }
            if (seq)              outp[((size_t)em * T_ + t) * H_ + j0 + eu] = heff;
            else if (t == T_ - 1) outp[(size_t)em * H_ + j0 + eu] = heff;
        }
        // inter-block flag barrier (skip after the chunk's last step)
        if (t + 1 < tend) {
            __syncthreads();                 // drains each thread's vmcnt -> h stores at LLC
            if (tid == 0)
                __hip_atomic_store(&myflags[myb * 32], (unsigned)(t + 1),
                                   __ATOMIC_RELAXED, __HIP_MEMORY_SCOPE_AGENT);
            if (tid < 128) {
                while (__hip_atomic_load(&myflags[tid * 32], __ATOMIC_RELAXED,
                                         __HIP_MEMORY_SCOPE_AGENT) < (unsigned)(t + 1))
                    __builtin_amdgcn_s_sleep(1);
            }
            __syncthreads();
        }
    }
    cbuf[dir * (B_ * H_) + em * H_ + j0 + eu] = Cl[tid];
}

// ---------------- final linear ----------------
__global__ void final_linear(const __bf16* __restrict__ h2f, const __bf16* __restrict__ h2b,
                             const float* __restrict__ lin_w, const float* __restrict__ lin_b,
                             float* __restrict__ out) {
    __shared__ float red[4];
    int b = blockIdx.x >> 1, c = blockIdx.x & 1;
    int tid = threadIdx.x;
    const __bf16* hb = h2b + (size_t)b * H_;
    const __bf16* hf = h2f + (size_t)b * H_;
    const float* w = lin_w + (size_t)c * (2 * H_);
    float s = 0.f;
    for (int j = tid; j < H_; j += 256)
        s += (float)hb[j] * w[j] + (float)hf[j] * w[H_ + j];
    for (int off = 32; off; off >>= 1) s += __shfl_down(s, off, 64);
    if ((tid & 63) == 0) red[tid >> 6] = s;
    __syncthreads();
    if (tid == 0)
        out[b * 2 + c] = red[0] + red[1] + red[2] + red[3] + lin_b[c];
}

// ---------------- launcher ----------------
extern "C" void kernel_launch(void* const* d_in, const int* in_sizes, int n_in,
                              void* d_out, int out_size, void* d_ws, size_t ws_size,
                              hipStream_t stream) {
    const int*   texts = (const int*)d_in[0];
    const int*   lens  = (const int*)d_in[1];
    const float* emb   = (const float*)d_in[2];
    const float* wih0f = (const float*)d_in[3];
    const float* whh0f = (const float*)d_in[4];
    const float* bih0f = (const float*)d_in[5];
    const float* bhh0f = (const float*)d_in[6];
    const float* wih0b = (const float*)d_in[7];
    const float* whh0b = (const float*)d_in[8];
    const float* bih0b = (const float*)d_in[9];
    const float* bhh0b = (const float*)d_in[10];
    const float* wih1f = (const float*)d_in[11];
    const float* whh1f = (const float*)d_in[12];
    const float* bih1f = (const float*)d_in[13];
    const float* bhh1f = (const float*)d_in[14];
    const float* wih1b = (const float*)d_in[15];
    const float* whh1b = (const float*)d_in[16];
    const float* bih1b = (const float*)d_in[17];
    const float* bhh1b = (const float*)d_in[18];
    const float* linw  = (const float*)d_in[19];
    const float* linb  = (const float*)d_in[20];

    char* ws = (char*)d_ws;
    __bf16*   hbuf  = (__bf16*)(ws + OFF_HBUF);
    unsigned* flags = (unsigned*)(ws + OFF_FLAGS);
    float*    cbuf  = (float*)(ws + OFF_CBUF);
    __bf16*   h2f   = (__bf16*)(ws + OFF_H2F);
    __bf16*   h2b   = (__bf16*)(ws + OFF_H2B);
    __bf16*   w0f   = (__bf16*)(ws + OFF_W0F);
    __bf16*   w0b   = (__bf16*)(ws + OFF_W0B);
    __bf16*   w1f   = (__bf16*)(ws + OFF_W1F);
    __bf16*   w1b   = (__bf16*)(ws + OFF_W1B);
    __bf16*   embp  = (__bf16*)(ws + OFF_EMB);
    __bf16*   outf  = (__bf16*)(ws + OFF_OUTF);
    __bf16*   outbr = (__bf16*)(ws + OFF_OUTB);
    __bf16*   xpf   = (__bf16*)(ws + OFF_XPF);
    __bf16*   xpb   = (__bf16*)(ws + OFF_XPB);

    if (ws_size < WS_NEED) return;

    hipMemsetAsync(ws, 0, SZ_ZERO, stream);      // hbuf + flags
    hipFuncSetAttribute((const void*)lstm_rec, hipFuncAttributeMaxDynamicSharedMemorySize, SMEM_REC);

    pad_w0 <<<dim3(G_, 2), 320, 0, stream>>>(wih0f, wih0b, w0f, w0b);
    cvt_w1 <<<dim3(G_, 2), 256, 0, stream>>>(wih1f, wih1b, w1f, w1b);
    cvt_emb<<<50000, 320, 0, stream>>>(emb, embp);

    __bf16* hb0 = hbuf;                          // layer-0 hbuf (2 slots x 2 dirs x 32768)
    __bf16* hb1 = hbuf + 131072;                 // layer-1 hbuf
    unsigned* fl0 = flags;                       // layer-0 flags (2 dirs x 128 x 32)
    unsigned* fl1 = flags + 2 * 128 * 32;        // layer-1 flags

    // -------- layer 0 --------
    for (int c = 0; c < NCH; ++c) {
        int t0 = c * CT_;
        gemm_l0c<<<1024, 256, 0, stream>>>(texts, lens, embp, w0f, bih0f, bhh0f, xpf, 0, t0);
        gemm_l0c<<<1024, 256, 0, stream>>>(texts, lens, embp, w0b, bih0b, bhh0b, xpb, 1, t0);
        lstm_rec<<<256, 256, SMEM_REC, stream>>>(xpf, xpb, whh0f, whh0b, lens,
                                                 hb0, cbuf, outf, outbr, fl0, t0, 1);
    }
    // -------- layer 1 --------
    for (int c = 0; c < NCH; ++c) {
        int t0 = c * CT_;
        gemm_l1c<<<1024, 256, 0, stream>>>(outf, outbr, lens, w1f, bih1f, bhh1f, xpf, 0, t0);
        gemm_l1c<<<1024, 256, 0, stream>>>(outf, outbr, lens, w1b, bih1b, bhh1b, xpb, 1, t0);
        lstm_rec<<<256, 256, SMEM_REC, stream>>>(xpf, xpb, whh1f, whh1b, lens,
                                                 hb1, cbuf, h2f, h2b, fl1, t0, 0);
    }
    final_linear<<<B_ * 2, 256, 0, stream>>>(h2f, h2b, linw, linb, (float*)d_out);
}